// Round 3
// baseline (366.417 us; speedup 1.0000x reference)
//
#include <hip/hip_runtime.h>
#include <math.h>

#define V 16
#define NC 10
#define NPX 1024
#define NPY 1024

static constexpr float TF = 1e-4f;
static constexpr float INV_TF = 1.0f / TF;

// ws layout in 4-byte units:
enum {
    WS_SP   = 0,             // sp[16]
    WS_D    = WS_SP + 16,    // d[16]
    WS_OD   = WS_D + 16,     // 1-d[16]
    WS_CL   = WS_OD + 16,    // Cl[16][16] dense (fallback path)
    WS_CR   = WS_CL + 256,   // Cr[16][16] dense
    WS_CLS  = WS_CR + 256,   // cls[16][10]
    WS_CLO  = WS_CLS + 160,  // int: left-child float-offset (childIdx*64) [16]
    WS_CRO  = WS_CLO + 16,   // int: right-child float-offset [16]
    WS_FLAG = WS_CRO + 16,   // int: all-rows-exactly-one-hot flag
    WS_CTR  = WS_FLAG + 1,   // int: work-stealing counter
    WS_TOTAL = WS_CTR + 1    // 754 * 4B ~ 3 KB
};

// Setup reproduces round-1's parameter numerics EXACTLY (libm expf, true
// division) — this problem amplifies ulp drift by ~1e4 through the
// T=1e-4 sigmoids, so parameter bits must not change.
__global__ void setup_kernel(const float* __restrict__ split_points,
                             const float* __restrict__ dir_logits,
                             const float* __restrict__ class_logits,
                             const float* __restrict__ child_logits,
                             float* __restrict__ ws) {
    const int t = threadIdx.x;
    int* wsi = (int*)ws;
    if (t == 0) { wsi[WS_CTR] = 0; wsi[WS_FLAG] = 1; }
    __syncthreads();

    if (t < 16) {
        float s = fminf(fmaxf(split_points[t], 0.1f), 0.9f);
        ws[WS_SP + t] = s;
        float dd = 1.0f / (1.0f + expf(-dir_logits[t]));
        ws[WS_D + t] = dd;
        ws[WS_OD + t] = 1.0f - dd;
    }
    if (t < 32) {
        // softmax(child_logits[n, side, :] / TF), dense write + one-hot probe
        const int n = t & (V - 1);
        const int side = t >> 4;             // 0 = left, 1 = right
        const float* row = child_logits + n * 2 * V + side * V;
        float u[V]; float m = -INFINITY;
        #pragma unroll
        for (int c = 0; c < V; ++c) { u[c] = row[c] * INV_TF; m = fmaxf(m, u[c]); }
        float sum = 0.0f;
        #pragma unroll
        for (int c = 0; c < V; ++c) { u[c] = expf(u[c] - m); sum += u[c]; }
        const int dense_at = (side ? WS_CR : WS_CL) + n * V;
        int cnt = 0, idx = 0; float pv = 0.0f;
        #pragma unroll
        for (int c = 0; c < V; ++c) {
            float p = u[c] / sum;            // division, as round 1
            ws[dense_at + c] = p;
            if (p != 0.0f) { ++cnt; idx = c; pv = p; }
        }
        // scatterable iff the row is EXACTLY one-hot with value 1.0f:
        // then the fmaf chain degenerates to a single exact add.
        if (cnt != 1 || pv != 1.0f) atomicAnd(&wsi[WS_FLAG], 0);
        wsi[(side ? WS_CRO : WS_CLO) + n] = idx * 64;
    } else if (t < 48) {
        const int n = t - 32;
        float uc[NC]; float mc = -INFINITY;
        #pragma unroll
        for (int c = 0; c < NC; ++c) { uc[c] = class_logits[n * NC + c] * INV_TF; mc = fmaxf(mc, uc[c]); }
        float sc = 0.0f;
        #pragma unroll
        for (int c = 0; c < NC; ++c) { uc[c] = expf(uc[c] - mc); sc += uc[c]; }
        #pragma unroll
        for (int c = 0; c < NC; ++c) ws[WS_CLS + n * NC + c] = uc[c] / sc;
    }
}

__device__ __forceinline__ float fast_sigmoid(float z) {
    // 1/(1+exp(-z)); saturates to exactly 1.0 / 0.0, matching the reference.
    // Identical to the round-1 (passing) helper.
    return __builtin_amdgcn_rcpf(1.0f + __expf(-z));
}

__global__ __launch_bounds__(256, 8) void fractal_kernel(
        const float* __restrict__ ws,
        int* __restrict__ ctr,
        const float* __restrict__ xs,
        const float* __restrict__ ys,
        const int* __restrict__ max_depth_p,
        float* __restrict__ out,
        int nt) {
    __shared__ float acc_s[4 * V * 64];        // per-wave 16x64 accumulator, 16 KB/block
    const int lane = threadIdx.x & 63;
    const int wave = threadIdx.x >> 6;
    float* A = acc_s + wave * (V * 64);
    const int* wsi = (const int*)ws;

    #pragma unroll
    for (int c = 0; c < V; ++c) A[c * 64 + lane] = 0.0f;  // exch keeps it zeroed

    const int depth = *max_depth_p;
    const bool onehot = wsi[WS_FLAG] != 0;     // uniform, loop-invariant

    for (;;) {
        int tile;
        if (lane == 0) tile = atomicAdd(ctr, 1);
        tile = __shfl(tile, 0, 64);
        if (tile >= nt) break;

        const int tx = tile >> 7;              // 128 tiles per dim (1024/8)
        const int ty = tile & 127;
        const int ix = tx * 8 + (lane >> 3);
        const int iy = ty * 8 + (lane & 7);
        const int p = ix * NPY + iy;

        const float x = xs[p];
        const float y = ys[p];

        float np[V];
        #pragma unroll
        for (int n = 0; n < V; ++n) np[n] = 0.0f;
        np[0] = 1.0f;
        float minx = 0.0f, maxx = 1.0f, miny = 0.0f, maxy = 1.0f;

        #pragma unroll 1
        for (int t = 0; t < depth; ++t) {
            const float rx = maxx - minx;
            const float ry = maxy - miny;
            float nxt[V];
            #pragma unroll
            for (int c = 0; c < V; ++c) nxt[c] = 0.0f;
            float sum_l = 0.0f, sum_r = 0.0f;
            float acc_lmaxx = 0.0f, acc_rminx = 0.0f;
            float acc_lmaxy = 0.0f, acc_rminy = 0.0f;

            if (onehot) {
                // Bit-exact vs the dense fmaf chain: every Cl/Cr entry is
                // exactly 0.0 (fmaf adds nothing, exactly) or exactly 1.0
                // (fmaf(v,1,x) == x+v, single rounding == ds_add). Scatter
                // r BEFORE l to match the fmaf nesting order; node order is
                // program order, preserved per-lane for LDS ops.
                #pragma unroll
                for (int n = 0; n < V; ++n) {
                    if (__any(np[n] != 0.0f)) {
                        const float spn = ws[WS_SP + n];
                        const float dn  = ws[WS_D + n];
                        const float odn = ws[WS_OD + n];
                        const float sx = fmaf(spn, rx, minx);
                        const float sy = fmaf(spn, ry, miny);
                        const float h = fast_sigmoid((sx - x) * INV_TF);
                        const float v = fast_sigmoid((sy - y) * INV_TF);
                        const float l = fmaf(dn, v, odn * h) * np[n];
                        const float r = np[n] - l;
                        sum_l += l;
                        sum_r += r;
                        acc_lmaxx = fmaf(fmaf(dn, maxx, odn * sx), l, acc_lmaxx);
                        acc_rminx = fmaf(fmaf(dn, minx, odn * sx), r, acc_rminx);
                        acc_lmaxy = fmaf(fmaf(odn, maxy, dn * sy), l, acc_lmaxy);
                        acc_rminy = fmaf(fmaf(odn, miny, dn * sy), r, acc_rminy);
                        atomicAdd(&A[wsi[WS_CRO + n] + lane], r);
                        atomicAdd(&A[wsi[WS_CLO + n] + lane], l);
                    }
                }
                #pragma unroll
                for (int c = 0; c < V; ++c)
                    nxt[c] = atomicExch(&A[c * 64 + lane], 0.0f);
            } else {
                // verbatim round-1 dense path
                #pragma unroll
                for (int n = 0; n < V; ++n) {
                    if (__any(np[n] != 0.0f)) {
                        const float spn = ws[WS_SP + n];
                        const float dn  = ws[WS_D + n];
                        const float odn = ws[WS_OD + n];
                        const float sx = fmaf(spn, rx, minx);
                        const float sy = fmaf(spn, ry, miny);
                        const float h = fast_sigmoid((sx - x) * INV_TF);
                        const float v = fast_sigmoid((sy - y) * INV_TF);
                        const float l = fmaf(dn, v, odn * h) * np[n];
                        const float r = np[n] - l;
                        sum_l += l;
                        sum_r += r;
                        acc_lmaxx = fmaf(fmaf(dn, maxx, odn * sx), l, acc_lmaxx);
                        acc_rminx = fmaf(fmaf(dn, minx, odn * sx), r, acc_rminx);
                        acc_lmaxy = fmaf(fmaf(odn, maxy, dn * sy), l, acc_lmaxy);
                        acc_rminy = fmaf(fmaf(odn, miny, dn * sy), r, acc_rminy);
                        #pragma unroll
                        for (int c = 0; c < V; ++c) {
                            nxt[c] = fmaf(l, ws[WS_CL + n * V + c],
                                     fmaf(r, ws[WS_CR + n * V + c], nxt[c]));
                        }
                    }
                }
            }

            float wsum = fmaxf(sum_l + sum_r, 1e-10f);
            const float inv_w = __builtin_amdgcn_rcpf(wsum);
            float psum = 0.0f;
            #pragma unroll
            for (int c = 0; c < V; ++c) psum += nxt[c];
            const float inv_p = __builtin_amdgcn_rcpf(fmaxf(psum, 1e-10f));
            #pragma unroll
            for (int c = 0; c < V; ++c) np[c] = nxt[c] * inv_p;

            const float nminx = fmaf(minx, sum_l, acc_rminx) * inv_w;
            const float nmaxx = fmaf(maxx, sum_r, acc_lmaxx) * inv_w;
            const float nminy = fmaf(miny, sum_l, acc_rminy) * inv_w;
            const float nmaxy = fmaf(maxy, sum_r, acc_lmaxy) * inv_w;
            minx = nminx; maxx = nmaxx; miny = nminy; maxy = nmaxy;
        }

        // class_probs = np @ cls
        float o[NC];
        #pragma unroll
        for (int c = 0; c < NC; ++c) o[c] = 0.0f;
        #pragma unroll
        for (int n = 0; n < V; ++n) {
            if (__any(np[n] != 0.0f)) {
                #pragma unroll
                for (int c = 0; c < NC; ++c)
                    o[c] = fmaf(np[n], ws[WS_CLS + n * NC + c], o[c]);
            }
        }

        float2* op = reinterpret_cast<float2*>(out + (size_t)p * NC);
        #pragma unroll
        for (int c = 0; c < NC / 2; ++c) op[c] = make_float2(o[2 * c], o[2 * c + 1]);
    }
}

extern "C" void kernel_launch(void* const* d_in, const int* in_sizes, int n_in,
                              void* d_out, int out_size, void* d_ws, size_t ws_size,
                              hipStream_t stream) {
    const float* split_points = (const float*)d_in[0];
    const float* dir_logits   = (const float*)d_in[1];
    const float* class_logits = (const float*)d_in[2];
    const float* child_logits = (const float*)d_in[3];
    const float* xs           = (const float*)d_in[4];
    const float* ys           = (const float*)d_in[5];
    const int*   max_depth    = (const int*)d_in[6];
    float* out = (float*)d_out;
    float* ws  = (float*)d_ws;   // needs WS_TOTAL*4 ~ 3 KB
    int* ctr   = (int*)ws + WS_CTR;

    hipLaunchKernelGGL(setup_kernel, dim3(1), dim3(64), 0, stream,
                       split_points, dir_logits, class_logits, child_logits, ws);

    const int B = in_sizes[4];                 // 1048576 points
    const int nt = B >> 6;                     // 16384 tiles (8x8 each)
    // persistent: 2048 blocks * 4 waves = 8192 waves = 256 CU * 32 waves/CU
    hipLaunchKernelGGL(fractal_kernel, dim3(2048), dim3(256), 0, stream,
                       ws, ctr, xs, ys, max_depth, out, nt);
}

// Round 4
// 192.048 us; speedup vs baseline: 1.9079x; 1.9079x over previous
//
#include <hip/hip_runtime.h>
#include <math.h>

#define V 16
#define NC 10
#define NPX 1024
#define NPY 1024

static constexpr float TF = 1e-4f;
static constexpr float INV_TF = 1.0f / TF;

// ws layout in 4-byte units.
// Mixing lists: for child c, contributor k: read LDS float at [off + lane],
// multiply by val, fmaf-accumulate. off = n*64 (r of node n) or 1024 + n*64
// (l of node n). Lists preserve round-1's fmaf order: n ascending, r before l.
enum {
    WS_SP   = 0,             // sp[16]
    WS_D    = WS_SP + 16,    // d[16]
    WS_OD   = WS_D + 16,     // 1-d[16]
    WS_MOFF = WS_OD + 16,    // int  [16][16] k-major: mix offsets (k*16+c)
    WS_MVAL = WS_MOFF + 256, // float[16][16] mix values
    WS_COFF = WS_MVAL + 256, // int  [16][16] k-major: class offsets (k*16+c, c<10)
    WS_CVAL = WS_COFF + 256, // float class values
    WS_K    = WS_CVAL + 256, // int: max mix contributors per child
    WS_K2   = WS_K + 1,      // int: max class contributors per class
    WS_TOTAL = WS_K2 + 1     // 1074 words ~ 4.3 KB
};

// Parameter numerics identical to round-1 (libm expf, true division):
// this problem amplifies ulp drift ~1e4x through the T=1e-4 sigmoids.
__global__ void setup_kernel(const float* __restrict__ split_points,
                             const float* __restrict__ dir_logits,
                             const float* __restrict__ class_logits,
                             const float* __restrict__ child_logits,
                             float* __restrict__ ws) {
    __shared__ float P[2][V][V];     // P[side][n][c] = softmax row
    __shared__ float CL[V][NC];      // cls rows
    __shared__ int cnt_mix[V];
    __shared__ int cnt_cls[NC];
    const int t = threadIdx.x;
    int* wsi = (int*)ws;

    if (t < V) {
        float s = fminf(fmaxf(split_points[t], 0.1f), 0.9f);
        ws[WS_SP + t] = s;
        float dd = 1.0f / (1.0f + expf(-dir_logits[t]));
        ws[WS_D + t] = dd;
        ws[WS_OD + t] = 1.0f - dd;
    }
    if (t < 2 * V) {
        const int n = t & (V - 1);
        const int side = t >> 4;             // 0 = left, 1 = right
        const float* row = child_logits + n * 2 * V + side * V;
        float u[V]; float m = -INFINITY;
        #pragma unroll
        for (int c = 0; c < V; ++c) { u[c] = row[c] * INV_TF; m = fmaxf(m, u[c]); }
        float sum = 0.0f;
        #pragma unroll
        for (int c = 0; c < V; ++c) { u[c] = expf(u[c] - m); sum += u[c]; }
        #pragma unroll
        for (int c = 0; c < V; ++c) P[side][n][c] = u[c] / sum;
    } else if (t < 3 * V) {
        const int n = t - 2 * V;
        float uc[NC]; float mc = -INFINITY;
        #pragma unroll
        for (int c = 0; c < NC; ++c) { uc[c] = class_logits[n * NC + c] * INV_TF; mc = fmaxf(mc, uc[c]); }
        float sc = 0.0f;
        #pragma unroll
        for (int c = 0; c < NC; ++c) { uc[c] = expf(uc[c] - mc); sc += uc[c]; }
        #pragma unroll
        for (int c = 0; c < NC; ++c) CL[n][c] = uc[c] / sc;
    }
    __syncthreads();

    if (t < V) {
        // build mix list for child c = t; order: n ascending, r before l
        int cnt = 0;
        for (int n = 0; n < V; ++n) {
            float vr = P[1][n][t];
            if (vr != 0.0f) { wsi[WS_MOFF + cnt * 16 + t] = n * 64;        ws[WS_MVAL + cnt * 16 + t] = vr; ++cnt; }
            float vl = P[0][n][t];
            if (vl != 0.0f) { wsi[WS_MOFF + cnt * 16 + t] = 1024 + n * 64; ws[WS_MVAL + cnt * 16 + t] = vl; ++cnt; }
        }
        cnt_mix[t] = cnt;
        for (int k = cnt; k < 16; ++k) {     // pad: coeff 0.0 * finite r0 = exact no-op
            wsi[WS_MOFF + k * 16 + t] = 0;
            ws[WS_MVAL + k * 16 + t] = 0.0f;
        }
    }
    if (t >= V && t < V + NC) {
        const int c = t - V;                 // class list, n ascending
        int cnt = 0;
        for (int n = 0; n < V; ++n) {
            float v = CL[n][c];
            if (v != 0.0f) { wsi[WS_COFF + cnt * 16 + c] = n * 64; ws[WS_CVAL + cnt * 16 + c] = v; ++cnt; }
        }
        cnt_cls[c] = cnt;
        for (int k = cnt; k < 16; ++k) {
            wsi[WS_COFF + k * 16 + c] = 0;
            ws[WS_CVAL + k * 16 + c] = 0.0f;
        }
    }
    __syncthreads();
    if (t == 0) {
        int K = 0;
        for (int c = 0; c < V; ++c) K = max(K, cnt_mix[c]);
        wsi[WS_K] = K;
        int K2 = 0;
        for (int c = 0; c < NC; ++c) K2 = max(K2, cnt_cls[c]);
        wsi[WS_K2] = K2;
    }
}

__device__ __forceinline__ float fast_sigmoid(float z) {
    // identical to round-1 (passing): saturates to exact 0.0 / 1.0
    return __builtin_amdgcn_rcpf(1.0f + __expf(-z));
}

__global__ __launch_bounds__(256, 5) void fractal_kernel(
        const float* __restrict__ ws,
        const float* __restrict__ xs,
        const float* __restrict__ ys,
        const int* __restrict__ max_depth_p,
        float* __restrict__ out,
        int nt) {
    // per-wave lane-private scratch: R[16][64] then L[16][64] (floats)
    __shared__ float lds[4 * 2048];          // 32 KB/block -> 5 blocks/CU
    const int lane = threadIdx.x & 63;
    const int wave = threadIdx.x >> 6;
    float* AR = lds + wave * 2048;           // r slots: AR[n*64 + lane]
                                             // l slots: AR[1024 + n*64 + lane]
    const int* wsi = (const int*)ws;

    const int tile = blockIdx.x * 4 + wave;  // static: one wave = one 8x8 tile
    if (tile >= nt) return;
    const int tx = tile >> 7;                // 128 tiles per dim
    const int ty = tile & 127;
    const int ix = tx * 8 + (lane >> 3);
    const int iy = ty * 8 + (lane & 7);
    const int p = ix * NPY + iy;

    const float x = xs[p];
    const float y = ys[p];
    const int depth = *max_depth_p;
    const int K  = wsi[WS_K];                // uniform, >=1
    const int K2 = wsi[WS_K2];

    float np[V];
    #pragma unroll
    for (int n = 0; n < V; ++n) np[n] = 0.0f;
    np[0] = 1.0f;
    float minx = 0.0f, maxx = 1.0f, miny = 0.0f, maxy = 1.0f;

    #pragma unroll 1
    for (int t = 0; t < depth; ++t) {
        const float rx = maxx - minx;
        const float ry = maxy - miny;
        float sum_l = 0.0f, sum_r = 0.0f;
        float acc_lmaxx = 0.0f, acc_rminx = 0.0f;
        float acc_lmaxy = 0.0f, acc_rminy = 0.0f;

        #pragma unroll
        for (int n = 0; n < V; ++n) {
            // zero-prob nodes contribute exact zeros -> skip is bit-exact
            if (__any(np[n] != 0.0f)) {
                const float spn = ws[WS_SP + n];   // uniform -> s_load
                const float dn  = ws[WS_D + n];
                const float odn = ws[WS_OD + n];
                const float sx = fmaf(spn, rx, minx);
                const float sy = fmaf(spn, ry, miny);
                const float h = fast_sigmoid((sx - x) * INV_TF);
                const float v = fast_sigmoid((sy - y) * INV_TF);
                const float l = fmaf(dn, v, odn * h) * np[n];
                const float r = np[n] - l;
                sum_l += l;
                sum_r += r;
                acc_lmaxx = fmaf(fmaf(dn, maxx, odn * sx), l, acc_lmaxx);
                acc_rminx = fmaf(fmaf(dn, minx, odn * sx), r, acc_rminx);
                acc_lmaxy = fmaf(fmaf(odn, maxy, dn * sy), l, acc_lmaxy);
                acc_rminy = fmaf(fmaf(odn, miny, dn * sy), r, acc_rminy);
                AR[n * 64 + lane] = r;             // plain lane-private stores
                AR[1024 + n * 64 + lane] = l;
            } else {
                AR[n * 64 + lane] = 0.0f;
                AR[1024 + n * 64 + lane] = 0.0f;
            }
        }

        // sparse mixing: bit-exact vs the dense fmaf chain (skipped entries
        // are exactly-zero coefficients; fmaf(x, 0.0, acc) == acc since
        // l,r >= 0; order preserved: per child, k ascending == n asc, r then l)
        float nxt[V];
        #pragma unroll
        for (int c = 0; c < V; ++c) nxt[c] = 0.0f;
        for (int k = 0; k < K; ++k) {              // uniform trip count
            #pragma unroll
            for (int c = 0; c < V; ++c) {
                const int off  = wsi[WS_MOFF + k * 16 + c];
                const float vv = ws[WS_MVAL + k * 16 + c];
                nxt[c] = fmaf(AR[off + lane], vv, nxt[c]);
            }
        }

        float wsum = fmaxf(sum_l + sum_r, 1e-10f);
        const float inv_w = __builtin_amdgcn_rcpf(wsum);
        float psum = 0.0f;
        #pragma unroll
        for (int c = 0; c < V; ++c) psum += nxt[c];
        const float inv_p = __builtin_amdgcn_rcpf(fmaxf(psum, 1e-10f));
        #pragma unroll
        for (int c = 0; c < V; ++c) np[c] = nxt[c] * inv_p;

        const float nminx = fmaf(minx, sum_l, acc_rminx) * inv_w;
        const float nmaxx = fmaf(maxx, sum_r, acc_lmaxx) * inv_w;
        const float nminy = fmaf(miny, sum_l, acc_rminy) * inv_w;
        const float nmaxy = fmaf(maxy, sum_r, acc_lmaxy) * inv_w;
        minx = nminx; maxx = nmaxx; miny = nminy; maxy = nmaxy;
    }

    // sparse class epilogue: np -> R slots, then per-class gathered fmaf chain
    #pragma unroll
    for (int n = 0; n < V; ++n) AR[n * 64 + lane] = np[n];

    float o[NC];
    #pragma unroll
    for (int c = 0; c < NC; ++c) o[c] = 0.0f;
    for (int k = 0; k < K2; ++k) {
        #pragma unroll
        for (int c = 0; c < NC; ++c) {
            const int off  = wsi[WS_COFF + k * 16 + c];
            const float vv = ws[WS_CVAL + k * 16 + c];
            o[c] = fmaf(AR[off + lane], vv, o[c]);
        }
    }

    float2* op = reinterpret_cast<float2*>(out + (size_t)p * NC);
    #pragma unroll
    for (int c = 0; c < NC / 2; ++c) op[c] = make_float2(o[2 * c], o[2 * c + 1]);
}

extern "C" void kernel_launch(void* const* d_in, const int* in_sizes, int n_in,
                              void* d_out, int out_size, void* d_ws, size_t ws_size,
                              hipStream_t stream) {
    const float* split_points = (const float*)d_in[0];
    const float* dir_logits   = (const float*)d_in[1];
    const float* class_logits = (const float*)d_in[2];
    const float* child_logits = (const float*)d_in[3];
    const float* xs           = (const float*)d_in[4];
    const float* ys           = (const float*)d_in[5];
    const int*   max_depth    = (const int*)d_in[6];
    float* out = (float*)d_out;
    float* ws  = (float*)d_ws;   // needs WS_TOTAL*4 ~ 4.3 KB

    hipLaunchKernelGGL(setup_kernel, dim3(1), dim3(64), 0, stream,
                       split_points, dir_logits, class_logits, child_logits, ws);

    const int B = in_sizes[4];               // 1048576 points
    const int nt = B >> 6;                   // 16384 tiles (8x8 each)
    hipLaunchKernelGGL(fractal_kernel, dim3(nt / 4), dim3(256), 0, stream,
                       ws, xs, ys, max_depth, out, nt);
}

// Round 5
// 157.500 us; speedup vs baseline: 2.3265x; 1.2194x over previous
//
#include <hip/hip_runtime.h>
#include <math.h>

#define V 16
#define NC 10
#define NPX 1024
#define NPY 1024

static constexpr float TF = 1e-4f;
static constexpr float INV_TF = 1.0f / TF;

// ws float layout (identical to round-1):
// [0:16) sp_clipped, [16:32) d, [32:48) 1-d,
// [48:304) Cl[V][V], [304:560) Cr[V][V], [560:720) cls[V][NC]
#define WS_SP 0
#define WS_D 16
#define WS_OD 32
#define WS_CL 48
#define WS_CR 304
#define WS_CLS 560

__global__ void setup_kernel(const float* __restrict__ split_points,
                             const float* __restrict__ dir_logits,
                             const float* __restrict__ class_logits,
                             const float* __restrict__ child_logits,
                             float* __restrict__ ws) {
    const int t = threadIdx.x;
    if (t < V) {
        float s = fminf(fmaxf(split_points[t], 0.1f), 0.9f);
        ws[WS_SP + t] = s;
        float dd = 1.0f / (1.0f + expf(-dir_logits[t]));
        ws[WS_D + t] = dd;
        ws[WS_OD + t] = 1.0f - dd;
        float u[V]; float m = -INFINITY;
        #pragma unroll
        for (int c = 0; c < V; ++c) { u[c] = child_logits[t * 2 * V + c] * INV_TF; m = fmaxf(m, u[c]); }
        float sum = 0.0f;
        #pragma unroll
        for (int c = 0; c < V; ++c) { u[c] = expf(u[c] - m); sum += u[c]; }
        #pragma unroll
        for (int c = 0; c < V; ++c) ws[WS_CL + t * V + c] = u[c] / sum;
    } else if (t < 2 * V) {
        const int n = t - V;
        float u[V]; float m = -INFINITY;
        #pragma unroll
        for (int c = 0; c < V; ++c) { u[c] = child_logits[n * 2 * V + V + c] * INV_TF; m = fmaxf(m, u[c]); }
        float sum = 0.0f;
        #pragma unroll
        for (int c = 0; c < V; ++c) { u[c] = expf(u[c] - m); sum += u[c]; }
        #pragma unroll
        for (int c = 0; c < V; ++c) ws[WS_CR + n * V + c] = u[c] / sum;
    } else if (t < 3 * V) {
        const int n = t - 2 * V;
        float u[NC]; float m = -INFINITY;
        #pragma unroll
        for (int c = 0; c < NC; ++c) { u[c] = class_logits[n * NC + c] * INV_TF; m = fmaxf(m, u[c]); }
        float sum = 0.0f;
        #pragma unroll
        for (int c = 0; c < NC; ++c) { u[c] = expf(u[c] - m); sum += u[c]; }
        #pragma unroll
        for (int c = 0; c < NC; ++c) ws[WS_CLS + n * NC + c] = u[c] / sum;
    }
}

__device__ __forceinline__ float fast_sigmoid(float z) {
    // 1/(1+exp(-z)); saturates to exactly 1.0 / 0.0 like the reference.
    return __builtin_amdgcn_rcpf(1.0f + __expf(-z));
}

__global__ __launch_bounds__(256) void fractal_kernel(
        const float* __restrict__ ws,
        const float* __restrict__ xs,
        const float* __restrict__ ys,
        const int* __restrict__ max_depth_p,
        float* __restrict__ out,
        int B) {
    const int lane = threadIdx.x & 63;
    const int wave = threadIdx.x >> 6;
    const int tile = blockIdx.x * 4 + wave;       // one wave = one 8x8 pixel tile
    if (tile >= (B >> 6)) return;
    const int tx = tile >> 7;                     // 1024/8 = 128 tiles per dim
    const int ty = tile & 127;
    const int ix = tx * 8 + (lane >> 3);
    const int iy = ty * 8 + (lane & 7);
    const int p = ix * NPY + iy;

    const float x = xs[p];
    const float y = ys[p];
    const int depth = *max_depth_p;

    float np[V];
    #pragma unroll
    for (int n = 0; n < V; ++n) np[n] = 0.0f;
    np[0] = 1.0f;
    float minx = 0.0f, maxx = 1.0f, miny = 0.0f, maxy = 1.0f;

    #pragma unroll 1
    for (int t = 0; t < depth; ++t) {
        const float rx = maxx - minx;
        const float ry = maxy - miny;
        float nxt[V];
        #pragma unroll
        for (int c = 0; c < V; ++c) nxt[c] = 0.0f;
        float sum_l = 0.0f, sum_r = 0.0f;
        float acc_lmaxx = 0.0f, acc_rminx = 0.0f;
        float acc_lmaxy = 0.0f, acc_rminy = 0.0f;

        #pragma unroll
        for (int n = 0; n < V; ++n) {
            // zero-prob nodes contribute exact zeros -> skip is bit-exact
            if (__any(np[n] != 0.0f)) {
                const float spn = ws[WS_SP + n];   // uniform -> s_load
                const float dn  = ws[WS_D + n];
                const float odn = ws[WS_OD + n];
                const float sx = fmaf(spn, rx, minx);
                const float sy = fmaf(spn, ry, miny);
                const float h = fast_sigmoid((sx - x) * INV_TF);
                const float v = fast_sigmoid((sy - y) * INV_TF);
                const float l = fmaf(dn, v, odn * h) * np[n];
                const float r = np[n] - l;
                sum_l += l;
                sum_r += r;
                acc_lmaxx = fmaf(fmaf(dn, maxx, odn * sx), l, acc_lmaxx);
                acc_rminx = fmaf(fmaf(dn, minx, odn * sx), r, acc_rminx);
                acc_lmaxy = fmaf(fmaf(odn, maxy, dn * sy), l, acc_lmaxy);
                acc_rminy = fmaf(fmaf(odn, miny, dn * sy), r, acc_rminy);
                #pragma unroll
                for (int c = 0; c < V; ++c) {
                    nxt[c] = fmaf(l, ws[WS_CL + n * V + c],
                             fmaf(r, ws[WS_CR + n * V + c], nxt[c]));
                }
            }
        }

        float wsum = fmaxf(sum_l + sum_r, 1e-10f);
        const float inv_w = __builtin_amdgcn_rcpf(wsum);
        float psum = 0.0f;
        #pragma unroll
        for (int c = 0; c < V; ++c) psum += nxt[c];
        const float inv_p = __builtin_amdgcn_rcpf(fmaxf(psum, 1e-10f));
        // Denoise: zero sub-1e-6 masses (2^-24 saturation leakage). Survivor
        // bits are identical to the unthresholded computation at this depth
        // (psum/inv_p include all entries); dropped mass contributes <= 1e-6
        // to the output directly. This collapses the active-node set to the
        // true geometric support, which is what the __any skip feeds on.
        #pragma unroll
        for (int c = 0; c < V; ++c) {
            float v = nxt[c] * inv_p;
            np[c] = (v < 1e-6f) ? 0.0f : v;
        }

        const float nminx = fmaf(minx, sum_l, acc_rminx) * inv_w;
        const float nmaxx = fmaf(maxx, sum_r, acc_lmaxx) * inv_w;
        const float nminy = fmaf(miny, sum_l, acc_rminy) * inv_w;
        const float nmaxy = fmaf(maxy, sum_r, acc_lmaxy) * inv_w;
        minx = nminx; maxx = nmaxx; miny = nminy; maxy = nmaxy;
    }

    // class_probs = np @ cls
    float o[NC];
    #pragma unroll
    for (int c = 0; c < NC; ++c) o[c] = 0.0f;
    #pragma unroll
    for (int n = 0; n < V; ++n) {
        if (__any(np[n] != 0.0f)) {
            #pragma unroll
            for (int c = 0; c < NC; ++c) o[c] = fmaf(np[n], ws[WS_CLS + n * NC + c], o[c]);
        }
    }

    float2* op = reinterpret_cast<float2*>(out + (size_t)p * NC);
    #pragma unroll
    for (int c = 0; c < NC / 2; ++c) op[c] = make_float2(o[2 * c], o[2 * c + 1]);
}

extern "C" void kernel_launch(void* const* d_in, const int* in_sizes, int n_in,
                              void* d_out, int out_size, void* d_ws, size_t ws_size,
                              hipStream_t stream) {
    const float* split_points = (const float*)d_in[0];
    const float* dir_logits   = (const float*)d_in[1];
    const float* class_logits = (const float*)d_in[2];
    const float* child_logits = (const float*)d_in[3];
    const float* xs           = (const float*)d_in[4];
    const float* ys           = (const float*)d_in[5];
    const int*   max_depth    = (const int*)d_in[6];
    float* out = (float*)d_out;
    float* ws  = (float*)d_ws;   // needs 720 floats = 2880 B

    hipLaunchKernelGGL(setup_kernel, dim3(1), dim3(64), 0, stream,
                       split_points, dir_logits, class_logits, child_logits, ws);

    const int B = in_sizes[4];                 // 1048576 points
    const int blocks = (B + 255) / 256;        // 4 waves/block, 1 tile/wave
    hipLaunchKernelGGL(fractal_kernel, dim3(blocks), dim3(256), 0, stream,
                       ws, xs, ys, max_depth, out, B);
}